// Round 1
// baseline (513.647 us; speedup 1.0000x reference)
//
#include <hip/hip_runtime.h>
#include <math.h>

// Problem constants
#define BB 64
#define SS 512
#define DD 768
#define DA 74
#define DV 47
#define PP 30
#define HP 96  // padded concat feature dim: 30+30+30 + 6 zero pad

__device__ __forceinline__ float dot4(float4 a, float4 b) {
    return a.x*b.x + a.y*b.y + a.z*b.z + a.w*b.w;
}

#define RSQRT_P 0.18257418583505537f  // 1/sqrt(30)

// ---------------------------------------------------------------------------
// Kernel A: fused projections. H[b*S+s][0:30]=hidden@Wt+bt, [30:60]=audio@Wa+ba,
// [60:90]=video@Wv+bv, [90:96]=0.  Grid: 512 blocks x 64 rows. Block 256.
// ---------------------------------------------------------------------------
__global__ __launch_bounds__(256) void proj_kernel(
    const float* __restrict__ hidden, const float* __restrict__ audio,
    const float* __restrict__ video,
    const float* __restrict__ Wt, const float* __restrict__ bt,
    const float* __restrict__ Wa, const float* __restrict__ ba,
    const float* __restrict__ Wv, const float* __restrict__ bv,
    float* __restrict__ H)
{
    __shared__ float lds[7296];  // 29.2 KB, unioned across phases
    const int tid = threadIdx.x;
    const int row0 = blockIdx.x * 64;
    const int cid = tid & 15;   // col-group: cols cid and cid+16
    const int rg  = tid >> 4;   // 16 row-groups; rows rg + 16*jr

    float accT[4][2] = {}, accA[4][2] = {}, accV[4][2] = {};

    // ---- text: K=768, 12 chunks of 64. xs[64][68], ws[32][68] (transposed)
    {
        float* xs = lds;            // 64*68 = 4352
        float* ws = lds + 4352;     // 32*68 = 2176
        for (int kc = 0; kc < 12; ++kc) {
            __syncthreads();
            #pragma unroll
            for (int i = 0; i < 4; ++i) {       // 1024 float4
                int idx = tid + i*256;
                int r = idx >> 4, c4 = idx & 15;
                float4 v = *(const float4*)&hidden[(size_t)(row0 + r)*768 + kc*64 + c4*4];
                *(float4*)&xs[r*68 + c4*4] = v;
            }
            #pragma unroll
            for (int i = 0; i < 8; ++i) {       // 2048 scalars
                int idx = tid + i*256;
                int k = idx >> 5, c = idx & 31;
                ws[c*68 + k] = (c < 30) ? Wt[(kc*64 + k)*30 + c] : 0.f;
            }
            __syncthreads();
            #pragma unroll
            for (int k4 = 0; k4 < 16; ++k4) {
                float4 w0 = *(const float4*)&ws[cid*68 + k4*4];
                float4 w1 = *(const float4*)&ws[(cid+16)*68 + k4*4];
                #pragma unroll
                for (int jr = 0; jr < 4; ++jr) {
                    float4 x = *(const float4*)&xs[(rg + 16*jr)*68 + k4*4];
                    accT[jr][0] += dot4(x, w0);
                    accT[jr][1] += dot4(x, w1);
                }
            }
        }
    }
    // ---- audio: K=74 (pad 76). xa[64][76], wa[32][76]
    {
        float* xa = lds;            // 64*76 = 4864
        float* wa = lds + 4864;     // 32*76 = 2432
        __syncthreads();
        for (int i = 0; i < 19; ++i) {          // 4864 scalars
            int idx = tid + i*256;
            int r = idx / 76, c = idx % 76;
            xa[idx] = (c < 74) ? audio[(size_t)(row0 + r)*74 + c] : 0.f;
        }
        for (int i = 0; i < 10; ++i) {          // 2432 scalars
            int idx = tid + i*256;
            if (idx < 2432) {
                int c = idx / 76, k = idx % 76;
                wa[idx] = (c < 30 && k < 74) ? Wa[k*30 + c] : 0.f;
            }
        }
        __syncthreads();
        #pragma unroll
        for (int k4 = 0; k4 < 19; ++k4) {
            float4 w0 = *(const float4*)&wa[cid*76 + k4*4];
            float4 w1 = *(const float4*)&wa[(cid+16)*76 + k4*4];
            #pragma unroll
            for (int jr = 0; jr < 4; ++jr) {
                float4 x = *(const float4*)&xa[(rg + 16*jr)*76 + k4*4];
                accA[jr][0] += dot4(x, w0);
                accA[jr][1] += dot4(x, w1);
            }
        }
    }
    // ---- video: K=47 (pad 52). xv[64][52], wv[32][52]
    {
        float* xv = lds;            // 64*52 = 3328
        float* wv = lds + 3328;     // 32*52 = 1664
        __syncthreads();
        for (int i = 0; i < 13; ++i) {          // 3328 scalars
            int idx = tid + i*256;
            int r = idx / 52, c = idx % 52;
            xv[idx] = (c < 47) ? video[(size_t)(row0 + r)*47 + c] : 0.f;
        }
        for (int i = 0; i < 7; ++i) {           // 1664 scalars
            int idx = tid + i*256;
            if (idx < 1664) {
                int c = idx / 52, k = idx % 52;
                wv[idx] = (c < 30 && k < 47) ? Wv[k*30 + c] : 0.f;
            }
        }
        __syncthreads();
        #pragma unroll
        for (int k4 = 0; k4 < 13; ++k4) {
            float4 w0 = *(const float4*)&wv[cid*52 + k4*4];
            float4 w1 = *(const float4*)&wv[(cid+16)*52 + k4*4];
            #pragma unroll
            for (int jr = 0; jr < 4; ++jr) {
                float4 x = *(const float4*)&xv[(rg + 16*jr)*52 + k4*4];
                accV[jr][0] += dot4(x, w0);
                accV[jr][1] += dot4(x, w1);
            }
        }
    }
    // ---- write H (with biases); zero the pad cols 90..95
    const int c1 = cid + 16;
    #pragma unroll
    for (int jr = 0; jr < 4; ++jr) {
        int r = rg + 16*jr;
        float* __restrict__ hr = H + (size_t)(row0 + r)*HP;
        hr[cid]      = accT[jr][0] + bt[cid];
        hr[30 + cid] = accA[jr][0] + ba[cid];
        hr[60 + cid] = accV[jr][0] + bv[cid];
        if (c1 < 30) {
            hr[c1]      = accT[jr][1] + bt[c1];
            hr[30 + c1] = accA[jr][1] + ba[c1];
            hr[60 + c1] = accV[jr][1] + bv[c1];
        }
        if (cid < 6) hr[90 + cid] = 0.f;
    }
}

// ---------------------------------------------------------------------------
// Kernel B: fusion_att tile = (H_b @ H_b^T)/sqrt(30); write relu to out2.
// Grid (8,8,64): 64x64 tile per block, 4x4 micro-tile per thread.
// ---------------------------------------------------------------------------
__global__ __launch_bounds__(256) void sim_kernel(
    const float* __restrict__ H, float* __restrict__ out2)
{
    __shared__ float as[64*100];
    __shared__ float bs[64*100];
    const int tid = threadIdx.x;
    const int b  = blockIdx.z;
    const int i0 = blockIdx.y * 64;
    const int j0 = blockIdx.x * 64;
    const float* __restrict__ Hb = H + (size_t)b * SS * HP;

    #pragma unroll
    for (int i = 0; i < 6; ++i) {               // 1536 float4 per side
        int idx = tid + i*256;
        int r = idx / 24, c4 = idx % 24;
        *(float4*)&as[r*100 + c4*4] = *(const float4*)&Hb[(size_t)(i0 + r)*HP + c4*4];
        *(float4*)&bs[r*100 + c4*4] = *(const float4*)&Hb[(size_t)(j0 + r)*HP + c4*4];
    }
    __syncthreads();

    const int tx = tid & 15, ty = tid >> 4;
    float acc[4][4] = {};
    #pragma unroll
    for (int k4 = 0; k4 < 24; ++k4) {
        float4 a[4], bq[4];
        #pragma unroll
        for (int ii = 0; ii < 4; ++ii) a[ii]  = *(const float4*)&as[(ty + 16*ii)*100 + k4*4];
        #pragma unroll
        for (int jj = 0; jj < 4; ++jj) bq[jj] = *(const float4*)&bs[(tx + 16*jj)*100 + k4*4];
        #pragma unroll
        for (int ii = 0; ii < 4; ++ii)
            #pragma unroll
            for (int jj = 0; jj < 4; ++jj)
                acc[ii][jj] += dot4(a[ii], bq[jj]);
    }

    float* __restrict__ o = out2 + (size_t)b * SS * SS;
    #pragma unroll
    for (int ii = 0; ii < 4; ++ii) {
        int i = i0 + ty + 16*ii;
        #pragma unroll
        for (int jj = 0; jj < 4; ++jj) {
            int j = j0 + tx + 16*jj;
            o[(size_t)i*SS + j] = fmaxf(acc[ii][jj] * RSQRT_P, 0.f);
        }
    }
}

// ---------------------------------------------------------------------------
// Kernel C: row-0 logits + softmax + PV.  fd[b][d] = sum_t p[t]*hidden[b][t][d]
//           + hidden[b][0][d].  Grid (64,4): batch x d-slice(192). Block 256.
// ---------------------------------------------------------------------------
__global__ __launch_bounds__(256) void pv_kernel(
    const float* __restrict__ H, const float* __restrict__ hidden,
    const float* __restrict__ amask, float* __restrict__ fd)
{
    __shared__ float sf[512];
    __shared__ float red[256];
    __shared__ float h0[96];
    const int tid = threadIdx.x;
    const int b = blockIdx.x;
    const int slice = blockIdx.y;
    const float* __restrict__ Hb = H + (size_t)b * SS * HP;

    if (tid < 24) *(float4*)&h0[tid*4] = *(const float4*)&Hb[tid*4];
    __syncthreads();

    // logits for row 0 (+ mask[b,0,t]; the row-constant mask term cancels)
    for (int t = tid; t < 512; t += 256) {
        const float* __restrict__ hr = Hb + (size_t)t*HP;
        float s = 0.f;
        #pragma unroll
        for (int k = 0; k < 96; k += 4) {
            float4 x = *(const float4*)&hr[k];
            s += x.x*h0[k] + x.y*h0[k+1] + x.z*h0[k+2] + x.w*h0[k+3];
        }
        sf[t] = s * RSQRT_P + amask[b*SS + t];
    }
    __syncthreads();
    // max reduce
    red[tid] = fmaxf(sf[tid], sf[tid + 256]);
    __syncthreads();
    for (int s2 = 128; s2 > 0; s2 >>= 1) {
        if (tid < s2) red[tid] = fmaxf(red[tid], red[tid + s2]);
        __syncthreads();
    }
    const float M = red[0];
    __syncthreads();
    // exp + sum reduce
    float e0 = __expf(sf[tid] - M), e1 = __expf(sf[tid + 256] - M);
    sf[tid] = e0; sf[tid + 256] = e1;
    red[tid] = e0 + e1;
    __syncthreads();
    for (int s2 = 128; s2 > 0; s2 >>= 1) {
        if (tid < s2) red[tid] += red[tid + s2];
        __syncthreads();
    }
    const float inv = 1.f / red[0];

    // PV over the 192-wide d slice
    if (tid < 192) {
        const int d = slice*192 + tid;
        float acc = 0.f;
        #pragma unroll 8
        for (int t = 0; t < 512; ++t)
            acc += sf[t] * hidden[((size_t)b*SS + t)*DD + d];
        fd[b*DD + d] = acc * inv + hidden[(size_t)b*SS*DD + d];
    }
}

// ---------------------------------------------------------------------------
// Kernel D: h = fd[64,768] @ Wd[768,768] + bd.  Grid (12,4): 64-col x 16-row
// tiles. Block 256 (tx=col 0..63, ty -> 4 rows each).
// ---------------------------------------------------------------------------
__global__ __launch_bounds__(256) void dense_kernel(
    const float* __restrict__ fd, const float* __restrict__ Wd,
    const float* __restrict__ bd, float* __restrict__ hout)
{
    __shared__ float fds[16*68];
    __shared__ float wds[64*68];
    const int tid = threadIdx.x;
    const int bn0 = blockIdx.x * 64, bm0 = blockIdx.y * 16;
    const int tx = tid & 63, ty = tid >> 6;
    float acc[4] = {};
    for (int kc = 0; kc < 12; ++kc) {
        __syncthreads();
        {   // fds: 256 float4, 1 per thread
            int r = tid >> 4, c4 = tid & 15;
            *(float4*)&fds[r*68 + c4*4] = *(const float4*)&fd[(size_t)(bm0 + r)*768 + kc*64 + c4*4];
        }
        #pragma unroll
        for (int i = 0; i < 4; ++i) {   // wds: 1024 float4
            int idx = tid + i*256;
            int k = idx >> 4, c4 = idx & 15;
            *(float4*)&wds[k*68 + c4*4] = *(const float4*)&Wd[(size_t)(kc*64 + k)*768 + bn0 + c4*4];
        }
        __syncthreads();
        #pragma unroll 16
        for (int k = 0; k < 64; ++k) {
            float w = wds[k*68 + tx];
            #pragma unroll
            for (int rr = 0; rr < 4; ++rr)
                acc[rr] += fds[(ty + 4*rr)*68 + k] * w;
        }
    }
    float bias = bd[bn0 + tx];
    #pragma unroll
    for (int rr = 0; rr < 4; ++rr)
        hout[(size_t)(bm0 + ty + 4*rr)*768 + bn0 + tx] = acc[rr] + bias;
}

// ---------------------------------------------------------------------------
// Kernel E: LayerNorm over 64 rows of 768 -> out1.  Grid 64, block 256.
// ---------------------------------------------------------------------------
__global__ __launch_bounds__(256) void ln_kernel(
    const float* __restrict__ hin, const float* __restrict__ g,
    const float* __restrict__ bta, float* __restrict__ out1)
{
    __shared__ float red[256];
    const int tid = threadIdx.x;
    const int row = blockIdx.x;
    const float* __restrict__ hr = hin + (size_t)row*768;
    float v0 = hr[tid], v1 = hr[tid + 256], v2 = hr[tid + 512];
    red[tid] = v0 + v1 + v2;
    __syncthreads();
    for (int s2 = 128; s2 > 0; s2 >>= 1) {
        if (tid < s2) red[tid] += red[tid + s2];
        __syncthreads();
    }
    const float mu = red[0] * (1.f/768.f);
    __syncthreads();
    float d0 = v0 - mu, d1 = v1 - mu, d2 = v2 - mu;
    red[tid] = d0*d0 + d1*d1 + d2*d2;
    __syncthreads();
    for (int s2 = 128; s2 > 0; s2 >>= 1) {
        if (tid < s2) red[tid] += red[tid + s2];
        __syncthreads();
    }
    const float var = red[0] * (1.f/768.f);
    const float inv = 1.f / sqrtf(var + 1e-12f);
    out1[(size_t)row*768 + tid]       = d0*inv*g[tid]       + bta[tid];
    out1[(size_t)row*768 + tid + 256] = d1*inv*g[tid + 256] + bta[tid + 256];
    out1[(size_t)row*768 + tid + 512] = d2*inv*g[tid + 512] + bta[tid + 512];
}

// ---------------------------------------------------------------------------
extern "C" void kernel_launch(void* const* d_in, const int* in_sizes, int n_in,
                              void* d_out, int out_size, void* d_ws, size_t ws_size,
                              hipStream_t stream) {
    (void)in_sizes; (void)n_in; (void)out_size; (void)ws_size;
    const float* hidden = (const float*)d_in[0];
    // d_in[1] pooled_output: unused by reference
    const float* audio  = (const float*)d_in[2];
    const float* video  = (const float*)d_in[3];
    const float* amask  = (const float*)d_in[4];
    const float* Wt = (const float*)d_in[5];
    const float* bt = (const float*)d_in[6];
    const float* Wa = (const float*)d_in[7];
    const float* ba = (const float*)d_in[8];
    const float* Wv = (const float*)d_in[9];
    const float* bv = (const float*)d_in[10];
    const float* Wd = (const float*)d_in[11];
    const float* bd = (const float*)d_in[12];
    const float* lng = (const float*)d_in[13];
    const float* lnb = (const float*)d_in[14];

    float* out1 = (float*)d_out;                      // [64,768]
    float* out2 = (float*)d_out + (size_t)BB*DD;      // [64,512,512]

    float* H    = (float*)d_ws;                       // 64*512*96 = 3,145,728 f
    float* fd   = H + (size_t)BB*SS*HP;               // 64*768
    float* hmid = fd + (size_t)BB*DD;                 // 64*768

    proj_kernel<<<dim3(512), 256, 0, stream>>>(hidden, audio, video,
                                               Wt, bt, Wa, ba, Wv, bv, H);
    sim_kernel<<<dim3(8, 8, 64), 256, 0, stream>>>(H, out2);
    pv_kernel<<<dim3(64, 4), 256, 0, stream>>>(H, hidden, amask, fd);
    dense_kernel<<<dim3(12, 4), 256, 0, stream>>>(fd, Wd, bd, hmid);
    ln_kernel<<<dim3(64), 256, 0, stream>>>(hmid, lng, lnb, out1);
}